// Round 17
// baseline (183.160 us; speedup 1.0000x reference)
//
#include <hip/hip_runtime.h>
#include <math.h>

#define S_LEN 2048
#define NB    2
#define CQ_   256
#define CC_   256
#define DH    50
#define KW    101
#define PS    100
#define RB    4     // rows per k_align block
#define HPAD  128   // zero-padded hidden width (branch-free loads)
#define WTH   1e-5f // phase-C weight skip threshold

// ---------------------------------------------------------------------------
// k_prep: WpT[c][j] = (j<100) ? Wp[j][c] : 0.   (exact R13 baseline)
// ---------------------------------------------------------------------------
__global__ __launch_bounds__(128) void k_prep(const float* __restrict__ Wp,
                                              float* __restrict__ WpT) {
  const int c = blockIdx.x, j = threadIdx.x;
  WpT[c * HPAD + j] = (j < PS) ? Wp[j * CC_ + c] : 0.0f;
}

// ---------------------------------------------------------------------------
// k_align: R16 depth-2 pipeline + ONE change: the ct base pointer is
// LAUNDERED into a VGPR (inline asm "+v"). Why: uniform ct reads compile to
// s_load, and SMEM results return OUT-OF-ORDER — lgkmcnt cannot wait
// selectively, so consuming cv0 forces lgkmcnt(0), draining cv1/cv2's
// in-flight loads too. That defeated every pipeline depth (R7/R16 neutral).
// With a VGPR base the reads become global_load_dwordx4 (64 lanes same
// address -> TA broadcast, one line) tracked by vmcnt: IN-ORDER, partial
// waits (vmcnt(N)) -> the depth-2 rotation finally overlaps.
// fmaf order + serial p j-sum BIT-IDENTICAL to R2..R16.
// ---------------------------------------------------------------------------
__global__ __launch_bounds__(384, 6) void k_align(const float* __restrict__ ct,
    const float* __restrict__ Wa, const float* __restrict__ WpT,
    const float* __restrict__ Vp, float* __restrict__ p_out,
    float* __restrict__ V_out) {
  const int r0  = blockIdx.x * RB;
  const int tid = threadIdx.x;

  __shared__ float red[RB][PS + 4];

  if (tid < CQ_) {
    const float* crow = ct + (size_t)r0 * CC_;
    asm volatile("" : "+v"(crow));   // force VGPR base -> vmcnt-tracked loads
    const float* wa = Wa + tid;
    float acc[RB];
#pragma unroll
    for (int r = 0; r < RB; ++r) acc[r] = 0.0f;

    float4 cv0[RB], cv1[RB], cv2[RB];
#pragma unroll
    for (int r = 0; r < RB; ++r) {
      cv0[r] = *(const float4*)&crow[r * CC_];        // quad 0
      cv1[r] = *(const float4*)&crow[r * CC_ + 4];    // quad 1
    }
    float w00 = wa[0 * CQ_], w01 = wa[1 * CQ_], w02 = wa[2 * CQ_], w03 = wa[3 * CQ_];
    float w10 = wa[4 * CQ_], w11 = wa[5 * CQ_], w12 = wa[6 * CQ_], w13 = wa[7 * CQ_];

    for (int c = 0; c < CC_ - 8; c += 4) {            // 62 iters: quads 0..61
      const int cf = c + 8;                           // prefetch quad c/4+2
#pragma unroll
      for (int r = 0; r < RB; ++r) cv2[r] = *(const float4*)&crow[r * CC_ + cf];
      const float w20 = wa[(size_t)(cf + 0) * CQ_];
      const float w21 = wa[(size_t)(cf + 1) * CQ_];
      const float w22 = wa[(size_t)(cf + 2) * CQ_];
      const float w23 = wa[(size_t)(cf + 3) * CQ_];
#pragma unroll
      for (int r = 0; r < RB; ++r) {
        float t = acc[r];
        t = fmaf(cv0[r].x, w00, t);
        t = fmaf(cv0[r].y, w01, t);
        t = fmaf(cv0[r].z, w02, t);
        t = fmaf(cv0[r].w, w03, t);
        acc[r] = t;
      }
#pragma unroll
      for (int r = 0; r < RB; ++r) { cv0[r] = cv1[r]; cv1[r] = cv2[r]; }
      w00 = w10; w01 = w11; w02 = w12; w03 = w13;
      w10 = w20; w11 = w21; w12 = w22; w13 = w23;
    }
#pragma unroll
    for (int r = 0; r < RB; ++r) {                    // epilogue quad 62
      float t = acc[r];
      t = fmaf(cv0[r].x, w00, t);
      t = fmaf(cv0[r].y, w01, t);
      t = fmaf(cv0[r].z, w02, t);
      t = fmaf(cv0[r].w, w03, t);
      acc[r] = t;
    }
#pragma unroll
    for (int r = 0; r < RB; ++r) {                    // epilogue quad 63
      float t = acc[r];
      t = fmaf(cv1[r].x, w10, t);
      t = fmaf(cv1[r].y, w11, t);
      t = fmaf(cv1[r].z, w12, t);
      t = fmaf(cv1[r].w, w13, t);
      acc[r] = t;
    }
#pragma unroll
    for (int r = 0; r < RB; ++r)
      V_out[(size_t)(r0 + r) * CQ_ + tid] = acc[r];
  } else {
    const float* crow = ct + (size_t)r0 * CC_;
    asm volatile("" : "+v"(crow));   // force VGPR base -> vmcnt-tracked loads
    const int j = tid - CQ_;
    const float* wh = WpT + j;
    float ah[RB];
#pragma unroll
    for (int r = 0; r < RB; ++r) ah[r] = 0.0f;

    float4 cv0[RB], cv1[RB], cv2[RB];
#pragma unroll
    for (int r = 0; r < RB; ++r) {
      cv0[r] = *(const float4*)&crow[r * CC_];
      cv1[r] = *(const float4*)&crow[r * CC_ + 4];
    }
    float w00 = wh[0 * HPAD], w01 = wh[1 * HPAD], w02 = wh[2 * HPAD], w03 = wh[3 * HPAD];
    float w10 = wh[4 * HPAD], w11 = wh[5 * HPAD], w12 = wh[6 * HPAD], w13 = wh[7 * HPAD];

    for (int c = 0; c < CC_ - 8; c += 4) {
      const int cf = c + 8;
#pragma unroll
      for (int r = 0; r < RB; ++r) cv2[r] = *(const float4*)&crow[r * CC_ + cf];
      const float w20 = wh[(size_t)(cf + 0) * HPAD];
      const float w21 = wh[(size_t)(cf + 1) * HPAD];
      const float w22 = wh[(size_t)(cf + 2) * HPAD];
      const float w23 = wh[(size_t)(cf + 3) * HPAD];
#pragma unroll
      for (int r = 0; r < RB; ++r) {
        float t = ah[r];                     // fmaf order x,y,z,w == R2..R16
        t = fmaf(cv0[r].x, w00, t);
        t = fmaf(cv0[r].y, w01, t);
        t = fmaf(cv0[r].z, w02, t);
        t = fmaf(cv0[r].w, w03, t);
        ah[r] = t;
      }
#pragma unroll
      for (int r = 0; r < RB; ++r) { cv0[r] = cv1[r]; cv1[r] = cv2[r]; }
      w00 = w10; w01 = w11; w02 = w12; w03 = w13;
      w10 = w20; w11 = w21; w12 = w22; w13 = w23;
    }
#pragma unroll
    for (int r = 0; r < RB; ++r) {                    // epilogue quad 62
      float t = ah[r];
      t = fmaf(cv0[r].x, w00, t);
      t = fmaf(cv0[r].y, w01, t);
      t = fmaf(cv0[r].z, w02, t);
      t = fmaf(cv0[r].w, w03, t);
      ah[r] = t;
    }
#pragma unroll
    for (int r = 0; r < RB; ++r) {                    // epilogue quad 63
      float t = ah[r];
      t = fmaf(cv1[r].x, w10, t);
      t = fmaf(cv1[r].y, w11, t);
      t = fmaf(cv1[r].z, w12, t);
      t = fmaf(cv1[r].w, w13, t);
      ah[r] = t;
    }
    if (j < PS) {
      const float vp = Vp[j];
#pragma unroll
      for (int r = 0; r < RB; ++r) red[r][j] = vp * tanhf(ah[r]);
    }
  }
  __syncthreads();
  if (tid < RB) {                         // serial j-sum: identical to R2..R16
    float s = 0.0f;
    for (int j = 0; j < PS; ++j) s += red[tid][j];
    p_out[r0 + tid] = (float)S_LEN * (1.0f / (1.0f + expf(-s)));
  }
}

// ---------------------------------------------------------------------------
// k_attn: EXACT R13 kernel (best: 111.3us). Two waves per row, coalesced
// phase-A loads, redundant per-wave softmax, parity-split phase C.
// V aliases out (block reads only its 2 rows, writes after barriers).
// ---------------------------------------------------------------------------
__global__ __launch_bounds__(256, 8) void k_attn(const float* __restrict__ q,
    const float* __restrict__ p_in, const float* V,   // aliases out
    float* out) {
  const int tid  = threadIdx.x;
  const int wid  = tid >> 6;
  const int rloc = wid >> 1;                // local row 0/1
  const int half = wid & 1;                 // group-range half
  const int row  = (blockIdx.x << 1) + rloc;
  const int lane = tid & 63;
  const int b    = row >> 11;

  __shared__ float ss[2][128];   // scores per local row (101..127 = -inf)
  __shared__ float sw[2][128];   // weights per local row
  __shared__ float sacc[4][CQ_]; // per-wave phase-C partials

  const float p  = p_in[row];
  const float tp = truncf(p);
  const float* qb = q + (size_t)b * S_LEN * CQ_;

  const int sub = lane >> 4;          // window-slot within group
  const int sl  = lane & 15;          // subgroup lane
  const int c4  = sl * 4;             // coalesced float4 column offset

  const float* vrow = V + (size_t)row * CQ_;
  const float4 v0 = *(const float4*)(vrow + c4);        // cols   0..63
  const float4 v1 = *(const float4*)(vrow + 64 + c4);   // cols  64..127
  const float4 v2 = *(const float4*)(vrow + 128 + c4);  // cols 128..191
  const float4 v3 = *(const float4*)(vrow + 192 + c4);  // cols 192..255

  if (lane >= KW - 64) ss[rloc][64 + lane] = -INFINITY;  // slots 101..127

  for (int gg = 0; gg < 13; gg += 2) {
    const int ga = half * 13 + gg;                 // groups for this wave
    const int ka = (ga << 2) + sub;                // uniform per 16-subgroup
    const int kb = ka + 4;                         // group ga+1 (<=26, masked)
    const float ta = p + (float)(ka - DH) + 1.0f;  // ref op order
    const float tb = p + (float)(kb - DH) + 1.0f;
    const int rawa = (int)ta;                      // trunc toward zero
    const int rawb = (int)tb;
    const bool oka = (rawa >= 1) && (rawa <= S_LEN) && (ka < KW);
    const bool okb = (rawb >= 1) && (rawb <= S_LEN) && (kb < KW);
    const float* qra = qb + (size_t)(oka ? rawa - 1 : 0) * CQ_;
    const float* qrb = qb + (size_t)(okb ? rawb - 1 : 0) * CQ_;

    // 8 loads in flight; each instr: 4 rows x 256B contiguous
    const float4 a0 = *(const float4*)(qra + c4);
    const float4 a1 = *(const float4*)(qra + 64 + c4);
    const float4 a2 = *(const float4*)(qra + 128 + c4);
    const float4 a3 = *(const float4*)(qra + 192 + c4);
    const float4 b0 = *(const float4*)(qrb + c4);
    const float4 b1 = *(const float4*)(qrb + 64 + c4);
    const float4 b2 = *(const float4*)(qrb + 128 + c4);
    const float4 b3 = *(const float4*)(qrb + 192 + c4);

    float t0 = a0.x * v0.x, t1 = a1.x * v1.x, t2 = a2.x * v2.x, t3 = a3.x * v3.x;
    t0 = fmaf(a0.y, v0.y, t0); t1 = fmaf(a1.y, v1.y, t1);
    t2 = fmaf(a2.y, v2.y, t2); t3 = fmaf(a3.y, v3.y, t3);
    t0 = fmaf(a0.z, v0.z, t0); t1 = fmaf(a1.z, v1.z, t1);
    t2 = fmaf(a2.z, v2.z, t2); t3 = fmaf(a3.z, v3.z, t3);
    t0 = fmaf(a0.w, v0.w, t0); t1 = fmaf(a1.w, v1.w, t1);
    t2 = fmaf(a2.w, v2.w, t2); t3 = fmaf(a3.w, v3.w, t3);
    float sA = (t0 + t1) + (t2 + t3);
    sA += __shfl_xor(sA, 1, 64);
    sA += __shfl_xor(sA, 2, 64);
    sA += __shfl_xor(sA, 4, 64);
    sA += __shfl_xor(sA, 8, 64);
    sA = oka ? sA : -INFINITY;
    if (sl == 0 && ka < 128) ss[rloc][ka] = sA;

    float u0 = b0.x * v0.x, u1 = b1.x * v1.x, u2 = b2.x * v2.x, u3 = b3.x * v3.x;
    u0 = fmaf(b0.y, v0.y, u0); u1 = fmaf(b1.y, v1.y, u1);
    u2 = fmaf(b2.y, v2.y, u2); u3 = fmaf(b3.y, v3.y, u3);
    u0 = fmaf(b0.z, v0.z, u0); u1 = fmaf(b1.z, v1.z, u1);
    u2 = fmaf(b2.z, v2.z, u2); u3 = fmaf(b3.z, v3.z, u3);
    u0 = fmaf(b0.w, v0.w, u0); u1 = fmaf(b1.w, v1.w, u1);
    u2 = fmaf(b2.w, v2.w, u2); u3 = fmaf(b3.w, v3.w, u3);
    float sB = (u0 + u1) + (u2 + u3);
    sB += __shfl_xor(sB, 1, 64);
    sB += __shfl_xor(sB, 2, 64);
    sB += __shfl_xor(sB, 4, 64);
    sB += __shfl_xor(sB, 8, 64);
    sB = okb ? sB : -INFINITY;
    if (sl == 0 && kb < 128) ss[rloc][kb] = sB;
  }
  __syncthreads();

  // ---- Phase B: redundant per wave (identical fp results per row) ----
  const float s0 = ss[rloc][lane];
  const float s1 = ss[rloc][64 + lane];

  float m = fmaxf(s0, s1);
#pragma unroll
  for (int off = 1; off < 64; off <<= 1) m = fmaxf(m, __shfl_xor(m, off, 64));

  const float e0 = __expf(s0 - m);                  // -inf -> 0
  const float e1 = __expf(s1 - m);
  float den = e0 + e1;
#pragma unroll
  for (int off = 1; off < 64; off <<= 1) den += __shfl_xor(den, off, 64);
  const float inv = 1.0f / den;

  float g0 = ((float)(lane - DH) + tp - p) / (float)DH;        // k = lane
  float g1 = ((float)(lane + (64 - DH)) + tp - p) / (float)DH; // k = 64+lane
  const float w0 = e0 * __expf(-2.0f * g0 * g0) * inv;
  const float w1 = e1 * __expf(-2.0f * g1 * g1) * inv;
  sw[rloc][lane] = w0;                              // dup write same value
  if (lane < KW - 64) sw[rloc][64 + lane] = w1;

  // ---- Phase C: survivors split by parity between the row's 2 waves ----
  unsigned long long m0 = __ballot(w0 > WTH);
  unsigned long long m1 = __ballot((lane < KW - 64) && (w1 > WTH));

  float4 acc = make_float4(0.0f, 0.0f, 0.0f, 0.0f);
  int cnt = 0;
  while ((m0 | m1) != 0ull) {
    int kk[4];
#pragma unroll
    for (int i = 0; i < 4; ++i) {
      int k = -1;
      if (m0)      { k = __builtin_ctzll(m0);      m0 &= m0 - 1; }
      else if (m1) { k = 64 + __builtin_ctzll(m1); m1 &= m1 - 1; }
      kk[i] = k;
    }
#pragma unroll
    for (int i = 0; i < 4; ++i) {
      if (kk[i] >= 0) {                             // wave-uniform
        if ((cnt & 1) == half) {                    // this wave's share
          const float wk = sw[rloc][kk[i]];
          const float t = p + (float)(kk[i] - DH) + 1.0f;
          const int r = (int)t - 1;                 // w>0 implies valid
          const float4 qv = *(const float4*)(qb + (size_t)r * CQ_ + lane * 4);
          acc.x = fmaf(wk, qv.x, acc.x);
          acc.y = fmaf(wk, qv.y, acc.y);
          acc.z = fmaf(wk, qv.z, acc.z);
          acc.w = fmaf(wk, qv.w, acc.w);
        }
        ++cnt;
      }
    }
  }
  *(float4*)&sacc[wid][lane * 4] = acc;
  __syncthreads();

  const int row0 = (blockIdx.x << 1);
  out[(size_t)row0 * CQ_ + tid]       = sacc[0][tid] + sacc[1][tid];
  out[(size_t)(row0 + 1) * CQ_ + tid] = sacc[2][tid] + sacc[3][tid];
}

// ---------------------------------------------------------------------------
extern "C" void kernel_launch(void* const* d_in, const int* in_sizes, int n_in,
                              void* d_out, int out_size, void* d_ws, size_t ws_size,
                              hipStream_t stream) {
  const float* q  = (const float*)d_in[0];
  const float* ct = (const float*)d_in[1];
  const float* Wa = (const float*)d_in[2];
  const float* Wp = (const float*)d_in[3];
  const float* Vp = (const float*)d_in[4];
  float* out = (float*)d_out;

  // ws (floats): p[4096] | WpT[256*128]  -> 147 KB
  float* ws     = (float*)d_ws;
  float* p_ws   = ws;
  float* WpT_ws = ws + NB * S_LEN;

  k_prep <<<CC_, HPAD, 0, stream>>>(Wp, WpT_ws);
  k_align<<<(NB * S_LEN) / RB, 384, 0, stream>>>(ct, Wa, WpT_ws, Vp, p_ws, out);
  k_attn <<<(NB * S_LEN) / 2, 256, 0, stream>>>(q, p_ws, out, out);
}

// Round 18
// 106.638 us; speedup vs baseline: 1.7176x; 1.7176x over previous
//
#include <hip/hip_runtime.h>
#include <math.h>

#define S_LEN 2048
#define NB    2
#define CQ_   256
#define CC_   256
#define DH    50
#define KW    101
#define PS    100
#define RB    4     // rows per k_align block
#define HPAD  128   // zero-padded hidden width (branch-free loads)
#define WTH   1e-5f // phase-C weight skip threshold

// ---------------------------------------------------------------------------
// k_prep: WpT[c][j] = (j<100) ? Wp[j][c] : 0.   (exact R13 baseline)
// ---------------------------------------------------------------------------
__global__ __launch_bounds__(128) void k_prep(const float* __restrict__ Wp,
                                              float* __restrict__ WpT) {
  const int c = blockIdx.x, j = threadIdx.x;
  WpT[c * HPAD + j] = (j < PS) ? Wp[j * CC_ + c] : 0.0f;
}

// ---------------------------------------------------------------------------
// k_align: SINGLE VARIABLE vs R13: K-loop in 16-column steps, straight-line
// loads (no manual rotation). Rationale: every wave redundantly issues the
// same ct s_load stream; at 64 iters x 4 s_load_dwordx4 the kernel is
// SMEM-issue/K$-throughput-bound (explains invariance to TLP [R14], pipeline
// depth [R7/R16], and the 3x regression when forced to VMEM [R17]). The 4
// consecutive dwordx4 per row now merge into ONE s_load_dwordx16 -> 4x fewer
// SMEM instructions (16 iters x 4 s_load_dwordx16).
// fmaf order per accumulator (ascending c; x,y,z,w) and the serial p j-sum
// are BIT-IDENTICAL to R2..R16.
// ---------------------------------------------------------------------------
__global__ __launch_bounds__(384, 6) void k_align(const float* __restrict__ ct,
    const float* __restrict__ Wa, const float* __restrict__ WpT,
    const float* __restrict__ Vp, float* __restrict__ p_out,
    float* __restrict__ V_out) {
  const int r0  = blockIdx.x * RB;
  const int tid = threadIdx.x;
  const float* crow = ct + (size_t)r0 * CC_;   // uniform base -> s_load

  __shared__ float red[RB][PS + 4];

  if (tid < CQ_) {
    const float* wa = Wa + tid;
    float acc[RB];
#pragma unroll
    for (int r = 0; r < RB; ++r) acc[r] = 0.0f;

    for (int c = 0; c < CC_; c += 16) {
      float4 cv[RB][4];
#pragma unroll
      for (int r = 0; r < RB; ++r)
#pragma unroll
        for (int qq = 0; qq < 4; ++qq)
          cv[r][qq] = *(const float4*)&crow[r * CC_ + c + qq * 4];  // merges to dwordx16
      float w[16];
#pragma unroll
      for (int k = 0; k < 16; ++k) w[k] = wa[(size_t)(c + k) * CQ_];
#pragma unroll
      for (int r = 0; r < RB; ++r) {
        float t = acc[r];
#pragma unroll
        for (int qq = 0; qq < 4; ++qq) {     // ascending c, x,y,z,w == R2..R16
          t = fmaf(cv[r][qq].x, w[qq * 4 + 0], t);
          t = fmaf(cv[r][qq].y, w[qq * 4 + 1], t);
          t = fmaf(cv[r][qq].z, w[qq * 4 + 2], t);
          t = fmaf(cv[r][qq].w, w[qq * 4 + 3], t);
        }
        acc[r] = t;
      }
    }
#pragma unroll
    for (int r = 0; r < RB; ++r)
      V_out[(size_t)(r0 + r) * CQ_ + tid] = acc[r];
  } else {
    const int j = tid - CQ_;
    const float* wh = WpT + j;
    float ah[RB];
#pragma unroll
    for (int r = 0; r < RB; ++r) ah[r] = 0.0f;

    for (int c = 0; c < CC_; c += 16) {
      float4 cv[RB][4];
#pragma unroll
      for (int r = 0; r < RB; ++r)
#pragma unroll
        for (int qq = 0; qq < 4; ++qq)
          cv[r][qq] = *(const float4*)&crow[r * CC_ + c + qq * 4];
      float w[16];
#pragma unroll
      for (int k = 0; k < 16; ++k) w[k] = wh[(size_t)(c + k) * HPAD];
#pragma unroll
      for (int r = 0; r < RB; ++r) {
        float t = ah[r];
#pragma unroll
        for (int qq = 0; qq < 4; ++qq) {     // ascending c, x,y,z,w == R2..R16
          t = fmaf(cv[r][qq].x, w[qq * 4 + 0], t);
          t = fmaf(cv[r][qq].y, w[qq * 4 + 1], t);
          t = fmaf(cv[r][qq].z, w[qq * 4 + 2], t);
          t = fmaf(cv[r][qq].w, w[qq * 4 + 3], t);
        }
        ah[r] = t;
      }
    }
    if (j < PS) {
      const float vp = Vp[j];
#pragma unroll
      for (int r = 0; r < RB; ++r) red[r][j] = vp * tanhf(ah[r]);
    }
  }
  __syncthreads();
  if (tid < RB) {                         // serial j-sum: identical to R2..R16
    float s = 0.0f;
    for (int j = 0; j < PS; ++j) s += red[tid][j];
    p_out[r0 + tid] = (float)S_LEN * (1.0f / (1.0f + expf(-s)));
  }
}

// ---------------------------------------------------------------------------
// k_attn: EXACT R13 kernel (best: 111.3us). Two waves per row, coalesced
// phase-A loads, redundant per-wave softmax, parity-split phase C.
// V aliases out (block reads only its 2 rows, writes after barriers).
// ---------------------------------------------------------------------------
__global__ __launch_bounds__(256, 8) void k_attn(const float* __restrict__ q,
    const float* __restrict__ p_in, const float* V,   // aliases out
    float* out) {
  const int tid  = threadIdx.x;
  const int wid  = tid >> 6;
  const int rloc = wid >> 1;                // local row 0/1
  const int half = wid & 1;                 // group-range half
  const int row  = (blockIdx.x << 1) + rloc;
  const int lane = tid & 63;
  const int b    = row >> 11;

  __shared__ float ss[2][128];   // scores per local row (101..127 = -inf)
  __shared__ float sw[2][128];   // weights per local row
  __shared__ float sacc[4][CQ_]; // per-wave phase-C partials

  const float p  = p_in[row];
  const float tp = truncf(p);
  const float* qb = q + (size_t)b * S_LEN * CQ_;

  const int sub = lane >> 4;          // window-slot within group
  const int sl  = lane & 15;          // subgroup lane
  const int c4  = sl * 4;             // coalesced float4 column offset

  const float* vrow = V + (size_t)row * CQ_;
  const float4 v0 = *(const float4*)(vrow + c4);        // cols   0..63
  const float4 v1 = *(const float4*)(vrow + 64 + c4);   // cols  64..127
  const float4 v2 = *(const float4*)(vrow + 128 + c4);  // cols 128..191
  const float4 v3 = *(const float4*)(vrow + 192 + c4);  // cols 192..255

  if (lane >= KW - 64) ss[rloc][64 + lane] = -INFINITY;  // slots 101..127

  for (int gg = 0; gg < 13; gg += 2) {
    const int ga = half * 13 + gg;                 // groups for this wave
    const int ka = (ga << 2) + sub;                // uniform per 16-subgroup
    const int kb = ka + 4;                         // group ga+1 (<=26, masked)
    const float ta = p + (float)(ka - DH) + 1.0f;  // ref op order
    const float tb = p + (float)(kb - DH) + 1.0f;
    const int rawa = (int)ta;                      // trunc toward zero
    const int rawb = (int)tb;
    const bool oka = (rawa >= 1) && (rawa <= S_LEN) && (ka < KW);
    const bool okb = (rawb >= 1) && (rawb <= S_LEN) && (kb < KW);
    const float* qra = qb + (size_t)(oka ? rawa - 1 : 0) * CQ_;
    const float* qrb = qb + (size_t)(okb ? rawb - 1 : 0) * CQ_;

    // 8 loads in flight; each instr: 4 rows x 256B contiguous
    const float4 a0 = *(const float4*)(qra + c4);
    const float4 a1 = *(const float4*)(qra + 64 + c4);
    const float4 a2 = *(const float4*)(qra + 128 + c4);
    const float4 a3 = *(const float4*)(qra + 192 + c4);
    const float4 b0 = *(const float4*)(qrb + c4);
    const float4 b1 = *(const float4*)(qrb + 64 + c4);
    const float4 b2 = *(const float4*)(qrb + 128 + c4);
    const float4 b3 = *(const float4*)(qrb + 192 + c4);

    float t0 = a0.x * v0.x, t1 = a1.x * v1.x, t2 = a2.x * v2.x, t3 = a3.x * v3.x;
    t0 = fmaf(a0.y, v0.y, t0); t1 = fmaf(a1.y, v1.y, t1);
    t2 = fmaf(a2.y, v2.y, t2); t3 = fmaf(a3.y, v3.y, t3);
    t0 = fmaf(a0.z, v0.z, t0); t1 = fmaf(a1.z, v1.z, t1);
    t2 = fmaf(a2.z, v2.z, t2); t3 = fmaf(a3.z, v3.z, t3);
    t0 = fmaf(a0.w, v0.w, t0); t1 = fmaf(a1.w, v1.w, t1);
    t2 = fmaf(a2.w, v2.w, t2); t3 = fmaf(a3.w, v3.w, t3);
    float sA = (t0 + t1) + (t2 + t3);
    sA += __shfl_xor(sA, 1, 64);
    sA += __shfl_xor(sA, 2, 64);
    sA += __shfl_xor(sA, 4, 64);
    sA += __shfl_xor(sA, 8, 64);
    sA = oka ? sA : -INFINITY;
    if (sl == 0 && ka < 128) ss[rloc][ka] = sA;

    float u0 = b0.x * v0.x, u1 = b1.x * v1.x, u2 = b2.x * v2.x, u3 = b3.x * v3.x;
    u0 = fmaf(b0.y, v0.y, u0); u1 = fmaf(b1.y, v1.y, u1);
    u2 = fmaf(b2.y, v2.y, u2); u3 = fmaf(b3.y, v3.y, u3);
    u0 = fmaf(b0.z, v0.z, u0); u1 = fmaf(b1.z, v1.z, u1);
    u2 = fmaf(b2.z, v2.z, u2); u3 = fmaf(b3.z, v3.z, u3);
    u0 = fmaf(b0.w, v0.w, u0); u1 = fmaf(b1.w, v1.w, u1);
    u2 = fmaf(b2.w, v2.w, u2); u3 = fmaf(b3.w, v3.w, u3);
    float sB = (u0 + u1) + (u2 + u3);
    sB += __shfl_xor(sB, 1, 64);
    sB += __shfl_xor(sB, 2, 64);
    sB += __shfl_xor(sB, 4, 64);
    sB += __shfl_xor(sB, 8, 64);
    sB = okb ? sB : -INFINITY;
    if (sl == 0 && kb < 128) ss[rloc][kb] = sB;
  }
  __syncthreads();

  // ---- Phase B: redundant per wave (identical fp results per row) ----
  const float s0 = ss[rloc][lane];
  const float s1 = ss[rloc][64 + lane];

  float m = fmaxf(s0, s1);
#pragma unroll
  for (int off = 1; off < 64; off <<= 1) m = fmaxf(m, __shfl_xor(m, off, 64));

  const float e0 = __expf(s0 - m);                  // -inf -> 0
  const float e1 = __expf(s1 - m);
  float den = e0 + e1;
#pragma unroll
  for (int off = 1; off < 64; off <<= 1) den += __shfl_xor(den, off, 64);
  const float inv = 1.0f / den;

  float g0 = ((float)(lane - DH) + tp - p) / (float)DH;        // k = lane
  float g1 = ((float)(lane + (64 - DH)) + tp - p) / (float)DH; // k = 64+lane
  const float w0 = e0 * __expf(-2.0f * g0 * g0) * inv;
  const float w1 = e1 * __expf(-2.0f * g1 * g1) * inv;
  sw[rloc][lane] = w0;                              // dup write same value
  if (lane < KW - 64) sw[rloc][64 + lane] = w1;

  // ---- Phase C: survivors split by parity between the row's 2 waves ----
  unsigned long long m0 = __ballot(w0 > WTH);
  unsigned long long m1 = __ballot((lane < KW - 64) && (w1 > WTH));

  float4 acc = make_float4(0.0f, 0.0f, 0.0f, 0.0f);
  int cnt = 0;
  while ((m0 | m1) != 0ull) {
    int kk[4];
#pragma unroll
    for (int i = 0; i < 4; ++i) {
      int k = -1;
      if (m0)      { k = __builtin_ctzll(m0);      m0 &= m0 - 1; }
      else if (m1) { k = 64 + __builtin_ctzll(m1); m1 &= m1 - 1; }
      kk[i] = k;
    }
#pragma unroll
    for (int i = 0; i < 4; ++i) {
      if (kk[i] >= 0) {                             // wave-uniform
        if ((cnt & 1) == half) {                    // this wave's share
          const float wk = sw[rloc][kk[i]];
          const float t = p + (float)(kk[i] - DH) + 1.0f;
          const int r = (int)t - 1;                 // w>0 implies valid
          const float4 qv = *(const float4*)(qb + (size_t)r * CQ_ + lane * 4);
          acc.x = fmaf(wk, qv.x, acc.x);
          acc.y = fmaf(wk, qv.y, acc.y);
          acc.z = fmaf(wk, qv.z, acc.z);
          acc.w = fmaf(wk, qv.w, acc.w);
        }
        ++cnt;
      }
    }
  }
  *(float4*)&sacc[wid][lane * 4] = acc;
  __syncthreads();

  const int row0 = (blockIdx.x << 1);
  out[(size_t)row0 * CQ_ + tid]       = sacc[0][tid] + sacc[1][tid];
  out[(size_t)(row0 + 1) * CQ_ + tid] = sacc[2][tid] + sacc[3][tid];
}

// ---------------------------------------------------------------------------
extern "C" void kernel_launch(void* const* d_in, const int* in_sizes, int n_in,
                              void* d_out, int out_size, void* d_ws, size_t ws_size,
                              hipStream_t stream) {
  const float* q  = (const float*)d_in[0];
  const float* ct = (const float*)d_in[1];
  const float* Wa = (const float*)d_in[2];
  const float* Wp = (const float*)d_in[3];
  const float* Vp = (const float*)d_in[4];
  float* out = (float*)d_out;

  // ws (floats): p[4096] | WpT[256*128]  -> 147 KB
  float* ws     = (float*)d_ws;
  float* p_ws   = ws;
  float* WpT_ws = ws + NB * S_LEN;

  k_prep <<<CC_, HPAD, 0, stream>>>(Wp, WpT_ws);
  k_align<<<(NB * S_LEN) / RB, 384, 0, stream>>>(ct, Wa, WpT_ws, Vp, p_ws, out);
  k_attn <<<(NB * S_LEN) / 2, 256, 0, stream>>>(q, p_ws, out, out);
}